// Round 1
// baseline (406.433 us; speedup 1.0000x reference)
//
#include <hip/hip_runtime.h>

typedef unsigned short u16;
typedef __attribute__((ext_vector_type(8))) short short8;
typedef __attribute__((ext_vector_type(4))) float f32x4;
typedef __attribute__((ext_vector_type(8))) unsigned short ushort8;
typedef __attribute__((ext_vector_type(4))) unsigned short ushort4v;

__device__ __forceinline__ u16 f2bf(float f) {
    unsigned int u = __float_as_uint(f);
    u += 0x7FFFu + ((u >> 16) & 1u);   // round-to-nearest-even
    return (u16)(u >> 16);
}
__device__ __forceinline__ float bf2f(u16 h) {
    return __uint_as_float(((unsigned int)h) << 16);
}

__device__ __forceinline__ void gld_lds16(const void* g, void* l) {
    __builtin_amdgcn_global_load_lds(
        (const __attribute__((address_space(1))) unsigned int*)g,
        (__attribute__((address_space(3))) unsigned int*)l,
        16, 0, 0);
}

// ---------------------------------------------------------------------------
// gemm_bt: C[M,N] = alpha * A[M,K] * B[N,K]^T   (both inputs bf16 row-major,
// inner dim K contiguous).  Tile 128x128, BK=32, 256 threads = 4 waves,
// each wave does a 64x64 quadrant as 4x4 MFMA 16x16x32 tiles.
// MODE 0: store bf16 C[row*ldc+col]
// MODE 1: store bf16 C[row*ldc+col]  (same as 0; alpha carries the scale)
// MODE 2: store bf16 transposed V^T: addr = ((row>>11)*768 + col)*2048 + (row&2047)
// MODE 3: store fp32 C[row*ldc+col]
// ---------------------------------------------------------------------------
template <int MODE>
__global__ __launch_bounds__(256) void gemm_bt(
    const u16* __restrict__ A, const u16* __restrict__ B, void* __restrict__ Cv,
    int K, int lda, int ldb, int ldc,
    long strideA, long strideB, long strideC, float alpha)
{
    __shared__ u16 As[128 * 32];
    __shared__ u16 Bs[128 * 32];

    const int bz = blockIdx.z;
    A += (long)bz * strideA;
    B += (long)bz * strideB;

    const int tm = blockIdx.y * 128;   // row tile (A rows / C rows)
    const int tn = blockIdx.x * 128;   // col tile (B rows / C cols)
    const int tid  = threadIdx.x;
    const int lane = tid & 63;
    const int wave = tid >> 6;
    const int wr = wave >> 1;          // wave row quadrant (0..1)
    const int wc = wave & 1;           // wave col quadrant (0..1)

    f32x4 acc[4][4] = {};

    const u16* a_base = As + ((wr * 64 + (lane & 15)) * 32) + ((lane >> 4) * 8);
    const u16* b_base = Bs + ((wc * 64 + (lane & 15)) * 32) + ((lane >> 4) * 8);

    const int c0 = tid;          // staging chunk ids: tid, tid+256
    const int c1 = tid + 256;
    const long ar0 = (long)(tm + (c0 >> 2)) * lda + (c0 & 3) * 8;
    const long ar1 = (long)(tm + (c1 >> 2)) * lda + (c1 & 3) * 8;
    const long br0 = (long)(tn + (c0 >> 2)) * ldb + (c0 & 3) * 8;
    const long br1 = (long)(tn + (c1 >> 2)) * ldb + (c1 & 3) * 8;

    for (int k0 = 0; k0 < K; k0 += 32) {
        __syncthreads();   // previous iteration's compute done before overwrite
        gld_lds16(A + ar0 + k0, (void*)(As + c0 * 8));
        gld_lds16(A + ar1 + k0, (void*)(As + c1 * 8));
        gld_lds16(B + br0 + k0, (void*)(Bs + c0 * 8));
        gld_lds16(B + br1 + k0, (void*)(Bs + c1 * 8));
        __syncthreads();   // drains vmcnt(0) before barrier

        short8 a[4], b[4];
#pragma unroll
        for (int i = 0; i < 4; ++i) a[i] = *(const short8*)(a_base + i * 16 * 32);
#pragma unroll
        for (int j = 0; j < 4; ++j) b[j] = *(const short8*)(b_base + j * 16 * 32);
#pragma unroll
        for (int i = 0; i < 4; ++i)
#pragma unroll
            for (int j = 0; j < 4; ++j)
                acc[i][j] = __builtin_amdgcn_mfma_f32_16x16x32_bf16(
                    a[i], b[j], acc[i][j], 0, 0, 0);
    }

    // Epilogue.  C/D layout (verified m89/m91): col = lane&15, row = (lane>>4)*4 + r
#pragma unroll
    for (int i = 0; i < 4; ++i) {
        const int row0 = tm + wr * 64 + i * 16 + ((lane >> 4) << 2);
#pragma unroll
        for (int j = 0; j < 4; ++j) {
            const int col = tn + wc * 64 + j * 16 + (lane & 15);
#pragma unroll
            for (int r = 0; r < 4; ++r) {
                const int row = row0 + r;
                const float val = acc[i][j][r] * alpha;
                if (MODE == 3) {
                    float* C = (float*)Cv + (long)bz * strideC;
                    C[(long)row * ldc + col] = val;
                } else if (MODE == 2) {
                    u16* C = (u16*)Cv;
                    C[((long)(row >> 11) * 768 + col) * 2048 + (row & 2047)] = f2bf(val);
                } else {
                    u16* C = (u16*)Cv + (long)bz * strideC;
                    C[(long)row * ldc + col] = f2bf(val);
                }
            }
        }
    }
}

// ---------------------------------------------------------------------------
__global__ __launch_bounds__(256) void cvt_x_kernel(
    const float4* __restrict__ x, ushort4v* __restrict__ out, int n4)
{
    int i = blockIdx.x * 256 + threadIdx.x;
    if (i < n4) {
        float4 f = x[i];
        ushort4v o;
        o.x = f2bf(f.x); o.y = f2bf(f.y); o.z = f2bf(f.z); o.w = f2bf(f.w);
        out[i] = o;
    }
}

// w[3][768][768] (m,d,o)  ->  wt[3][768][768] (m,o,d), bf16
__global__ __launch_bounds__(256) void cvt_w_kernel(
    const float* __restrict__ w, u16* __restrict__ wt)
{
    int i = blockIdx.x * 256 + threadIdx.x;   // total 3*768*768
    int d = i % 768;
    int o = (i / 768) % 768;
    int m = i / (768 * 768);
    wt[i] = f2bf(w[((long)m * 768 + d) * 768 + o]);
}

// one block per row, 2048 bf16 logits in-place -> softmax probs (bf16)
__global__ __launch_bounds__(256) void softmax_kernel(u16* __restrict__ S)
{
    const long row = blockIdx.x;
    u16* p = S + row * 2048;
    const int t = threadIdx.x;
    const int lane = t & 63;
    const int wave = t >> 6;
    __shared__ float red[8];

    ushort8 raw = *(const ushort8*)(p + t * 8);
    float v[8];
    float m = -1e30f;
#pragma unroll
    for (int i = 0; i < 8; ++i) { v[i] = bf2f(raw[i]); m = fmaxf(m, v[i]); }
#pragma unroll
    for (int off = 1; off < 64; off <<= 1) m = fmaxf(m, __shfl_xor(m, off, 64));
    if (lane == 0) red[wave] = m;
    __syncthreads();
    m = fmaxf(fmaxf(red[0], red[1]), fmaxf(red[2], red[3]));

    float s = 0.f;
#pragma unroll
    for (int i = 0; i < 8; ++i) { v[i] = __expf(v[i] - m); s += v[i]; }
#pragma unroll
    for (int off = 1; off < 64; off <<= 1) s += __shfl_xor(s, off, 64);
    if (lane == 0) red[4 + wave] = s;
    __syncthreads();
    s = (red[4] + red[5]) + (red[6] + red[7]);

    const float inv = 1.0f / s;
    ushort8 out;
#pragma unroll
    for (int i = 0; i < 8; ++i) out[i] = f2bf(v[i] * inv);
    *(ushort8*)(p + t * 8) = out;
}

// ---------------------------------------------------------------------------
extern "C" void kernel_launch(void* const* d_in, const int* in_sizes, int n_in,
                              void* d_out, int out_size, void* d_ws, size_t ws_size,
                              hipStream_t stream)
{
    const float* x  = (const float*)d_in[0];   // [8,2048,768]
    const float* wk = (const float*)d_in[1];   // [3,768,768]
    float* out = (float*)d_out;                // [8,2048,768]

    const float SCALE = 0.125f;  // 1/sqrt(64)

    char* ws = (char*)d_ws;
    u16* xbf = (u16*)(ws);                       // 16384x768        25.2 MB
    u16* wt  = (u16*)(ws + 25165824);            // 3x768x768 (W^T)   3.5 MB
    u16* qbf = (u16*)(ws + 28704768);            // 16384x768        25.2 MB
    u16* kbf = (u16*)(ws + 53870592);            // 16384x768        25.2 MB
    u16* vt  = (u16*)(ws + 79036416);            // 8x768x2048       25.2 MB
    u16* S   = (u16*)(ws + 104202240);           // 8x2048x2048      67.1 MB

    // 1. conversions
    cvt_x_kernel<<<dim3(12288), dim3(256), 0, stream>>>(
        (const float4*)x, (ushort4v*)xbf, 3145728);
    cvt_w_kernel<<<dim3(6912), dim3(256), 0, stream>>>(wk, wt);

    // 2. QKV projections: [16384,768] x Wt[768,768]^T
    gemm_bt<0><<<dim3(6, 128, 1), dim3(256), 0, stream>>>(
        xbf, wt,                qbf, 768, 768, 768, 768, 0, 0, 0, 1.0f);
    gemm_bt<0><<<dim3(6, 128, 1), dim3(256), 0, stream>>>(
        xbf, wt + 768 * 768,    kbf, 768, 768, 768, 768, 0, 0, 0, 1.0f);
    gemm_bt<2><<<dim3(6, 128, 1), dim3(256), 0, stream>>>(
        xbf, wt + 2 * 768 * 768, vt, 768, 768, 768, 2048, 0, 0, 0, 1.0f);

    // 3. logits: S_b = scale * Q_b K_b^T   [2048,2048] per batch
    gemm_bt<1><<<dim3(16, 16, 8), dim3(256), 0, stream>>>(
        qbf, kbf, S, 768, 768, 768, 2048,
        (long)2048 * 768, (long)2048 * 768, (long)2048 * 2048, SCALE);

    // 4. softmax rows (in place, bf16)
    softmax_kernel<<<dim3(16384), dim3(256), 0, stream>>>(S);

    // 5. out_b = A_b V_b  = A[2048,2048] x Vt[768,2048]^T -> fp32
    gemm_bt<3><<<dim3(6, 16, 8), dim3(256), 0, stream>>>(
        S, vt, out, 2048, 2048, 2048, 768,
        (long)2048 * 2048, (long)768 * 2048, (long)2048 * 768, 1.0f);
}

// Round 2
// 349.072 us; speedup vs baseline: 1.1643x; 1.1643x over previous
//
#include <hip/hip_runtime.h>

typedef unsigned short u16;
typedef __attribute__((ext_vector_type(8))) short short8;
typedef __attribute__((ext_vector_type(4))) float f32x4;
typedef __attribute__((ext_vector_type(8))) unsigned short ushort8;
typedef __attribute__((ext_vector_type(4))) unsigned short ushort4v;

__device__ __forceinline__ u16 f2bf(float f) {
    unsigned int u = __float_as_uint(f);
    u += 0x7FFFu + ((u >> 16) & 1u);   // round-to-nearest-even
    return (u16)(u >> 16);
}
__device__ __forceinline__ float bf2f(u16 h) {
    return __uint_as_float(((unsigned int)h) << 16);
}

__device__ __forceinline__ void gld_lds16(const void* g, void* l) {
    __builtin_amdgcn_global_load_lds(
        (const __attribute__((address_space(1))) unsigned int*)g,
        (__attribute__((address_space(3))) unsigned int*)l,
        16, 0, 0);
}

// ---------------------------------------------------------------------------
// One GEMM template, three modes, all C = alpha * A[M,K] * B[N,K]^T, bf16 in.
// Tile 128x128, BK=32, 4 waves, 4x4 MFMA 16x16x32 per wave.
//
// LDS layout is XOR-swizzled for bank-conflict-free ds_read_b128:
//   chunk (row, kc) of 8 bf16 lives at 16B-granule  g = row*4 + (kc ^ ((row>>1)&3))
// Write side realizes the swizzle by permuting per-lane GLOBAL addresses
// (stays inside each row's 64B line -> no coalescing loss); LDS destination
// remains lane-contiguous as global_load_lds requires.
//
// MODE 0: fused QKV projection. A=xbf[16384,768], B=wt[2304,768] (3 W^T stacked)
//         grid 2304: f&7=xcd owns x row-tiles [16*xcd,16*xcd+16); c=u>>4 picks
//         W col-tile 0..17 -> which = c/6 routes to Q / K / V^T outputs.
// MODE 1: logits S_b = 0.125 * Q_b K_b^T. grid 2048: f&7 = batch = xcd,
//         panels of 4 row-tiles so live set (Q panel + K_b) < 4MB L2.
// MODE 2: out_b = A_b V_b (A=softmaxed S bf16, B=V^T), fp32 out. grid 768:
//         f&7 = batch, panels of 2 row-tiles.
// ---------------------------------------------------------------------------
template <int MODE>
__global__ __launch_bounds__(256) void gemm_bt(
    const u16* __restrict__ A, const u16* __restrict__ B,
    void* __restrict__ O0, void* __restrict__ O1, void* __restrict__ O2,
    float alpha)
{
    constexpr int K   = (MODE == 2) ? 2048 : 768;
    constexpr int lda = (MODE == 2) ? 2048 : 768;
    constexpr int ldb = (MODE == 2) ? 2048 : 768;

    __shared__ u16 As[128 * 32];
    __shared__ u16 Bs[128 * 32];

    const int f = blockIdx.x;
    const int xcd = f & 7;
    const int u = f >> 3;

    int tm, bn, cn, which = 0;
    long aoff = 0, boff = 0;
    if constexpr (MODE == 0) {
        const int c = u >> 4;            // 0..17
        const int rl = u & 15;
        tm = (xcd * 16 + rl) * 128;
        bn = c * 128;
        which = c / 6;
        cn = (c % 6) * 128;
    } else if constexpr (MODE == 1) {
        const int p = u >> 6, t = u & 63, c = t >> 2, rl = t & 3;
        tm = (p * 4 + rl) * 128;
        bn = cn = c * 128;
        aoff = (long)xcd * 2048 * 768;
        boff = aoff;
    } else {
        const int p = u / 12, t = u % 12, c = t >> 1, rl = t & 1;
        tm = (p * 2 + rl) * 128;
        bn = cn = c * 128;
        aoff = (long)xcd * 2048 * 2048;
        boff = (long)xcd * 768 * 2048;
    }

    const u16* Ab = A + aoff;
    const u16* Bb = B + boff;

    const int tid  = threadIdx.x;
    const int lane = tid & 63;
    const int wave = tid >> 6;
    const int wr = wave >> 1;
    const int wc = wave & 1;

    f32x4 acc[4][4] = {};

    // swizzled read bases
    const int swz = ((lane >> 4) ^ ((lane >> 1) & 3)) * 8;
    const u16* a_base = As + (wr * 64 + (lane & 15)) * 32 + swz;
    const u16* b_base = Bs + (wc * 64 + (lane & 15)) * 32 + swz;

    // staging: slot s holds global chunk (row = s>>2, kc = (s&3) ^ ((row>>1)&3))
    const int s0 = tid, s1 = tid + 256;
    const int r0 = s0 >> 2, kc0 = (s0 & 3) ^ ((r0 >> 1) & 3);
    const int r1 = s1 >> 2, kc1 = (s1 & 3) ^ ((r1 >> 1) & 3);
    const long ar0 = (long)(tm + r0) * lda + kc0 * 8;
    const long ar1 = (long)(tm + r1) * lda + kc1 * 8;
    const long br0 = (long)(bn + r0) * ldb + kc0 * 8;
    const long br1 = (long)(bn + r1) * ldb + kc1 * 8;

    for (int k0 = 0; k0 < K; k0 += 32) {
        __syncthreads();
        gld_lds16(Ab + ar0 + k0, (void*)(As + s0 * 8));
        gld_lds16(Ab + ar1 + k0, (void*)(As + s1 * 8));
        gld_lds16(Bb + br0 + k0, (void*)(Bs + s0 * 8));
        gld_lds16(Bb + br1 + k0, (void*)(Bs + s1 * 8));
        __syncthreads();

        short8 a[4], b[4];
#pragma unroll
        for (int i = 0; i < 4; ++i) a[i] = *(const short8*)(a_base + i * 16 * 32);
#pragma unroll
        for (int j = 0; j < 4; ++j) b[j] = *(const short8*)(b_base + j * 16 * 32);
#pragma unroll
        for (int i = 0; i < 4; ++i)
#pragma unroll
            for (int j = 0; j < 4; ++j)
                acc[i][j] = __builtin_amdgcn_mfma_f32_16x16x32_bf16(
                    a[i], b[j], acc[i][j], 0, 0, 0);
    }

    // Epilogue. C/D layout: col = lane&15, row = (lane>>4)*4 + r
#pragma unroll
    for (int i = 0; i < 4; ++i) {
        const int row0 = tm + wr * 64 + i * 16 + ((lane >> 4) << 2);
#pragma unroll
        for (int j = 0; j < 4; ++j) {
            const int col = cn + wc * 64 + j * 16 + (lane & 15);
#pragma unroll
            for (int r = 0; r < 4; ++r) {
                const int row = row0 + r;
                const float val = acc[i][j][r] * alpha;
                if constexpr (MODE == 0) {
                    if (which == 0)
                        ((u16*)O0)[(long)row * 768 + col] = f2bf(val);
                    else if (which == 1)
                        ((u16*)O1)[(long)row * 768 + col] = f2bf(val);
                    else  // V^T: [b, col, s]
                        ((u16*)O2)[((long)(row >> 11) * 768 + col) * 2048 + (row & 2047)] = f2bf(val);
                } else if constexpr (MODE == 1) {
                    ((u16*)O0)[(long)xcd * 2048 * 2048 + (long)row * 2048 + col] = f2bf(val);
                } else {
                    ((float*)O0)[(long)xcd * 2048 * 768 + (long)row * 768 + col] = val;
                }
            }
        }
    }
}

// ---------------------------------------------------------------------------
__global__ __launch_bounds__(256) void cvt_x_kernel(
    const float4* __restrict__ x, ushort4v* __restrict__ out, int n4)
{
    int i = blockIdx.x * 256 + threadIdx.x;
    if (i < n4) {
        float4 f = x[i];
        ushort4v o;
        o.x = f2bf(f.x); o.y = f2bf(f.y); o.z = f2bf(f.z); o.w = f2bf(f.w);
        out[i] = o;
    }
}

// w[3][768][768] (m,d,o)  ->  wt[3][768][768] (m,o,d), bf16
__global__ __launch_bounds__(256) void cvt_w_kernel(
    const float* __restrict__ w, u16* __restrict__ wt)
{
    int i = blockIdx.x * 256 + threadIdx.x;   // total 3*768*768
    int d = i % 768;
    int o = (i / 768) % 768;
    int m = i / (768 * 768);
    wt[i] = f2bf(w[((long)m * 768 + d) * 768 + o]);
}

// one block per row, 2048 bf16 logits in-place -> softmax probs (bf16)
__global__ __launch_bounds__(256) void softmax_kernel(u16* __restrict__ S)
{
    const long row = blockIdx.x;
    u16* p = S + row * 2048;
    const int t = threadIdx.x;
    const int lane = t & 63;
    const int wave = t >> 6;
    __shared__ float red[8];

    ushort8 raw = *(const ushort8*)(p + t * 8);
    float v[8];
    float m = -1e30f;
#pragma unroll
    for (int i = 0; i < 8; ++i) { v[i] = bf2f(raw[i]); m = fmaxf(m, v[i]); }
#pragma unroll
    for (int off = 1; off < 64; off <<= 1) m = fmaxf(m, __shfl_xor(m, off, 64));
    if (lane == 0) red[wave] = m;
    __syncthreads();
    m = fmaxf(fmaxf(red[0], red[1]), fmaxf(red[2], red[3]));

    float s = 0.f;
#pragma unroll
    for (int i = 0; i < 8; ++i) { v[i] = __expf(v[i] - m); s += v[i]; }
#pragma unroll
    for (int off = 1; off < 64; off <<= 1) s += __shfl_xor(s, off, 64);
    if (lane == 0) red[4 + wave] = s;
    __syncthreads();
    s = (red[4] + red[5]) + (red[6] + red[7]);

    const float inv = 1.0f / s;
    ushort8 out;
#pragma unroll
    for (int i = 0; i < 8; ++i) out[i] = f2bf(v[i] * inv);
    *(ushort8*)(p + t * 8) = out;
}

// ---------------------------------------------------------------------------
extern "C" void kernel_launch(void* const* d_in, const int* in_sizes, int n_in,
                              void* d_out, int out_size, void* d_ws, size_t ws_size,
                              hipStream_t stream)
{
    const float* x  = (const float*)d_in[0];   // [8,2048,768]
    const float* wk = (const float*)d_in[1];   // [3,768,768]
    float* out = (float*)d_out;                // [8,2048,768]

    char* ws = (char*)d_ws;
    u16* xbf = (u16*)(ws);                       // 16384x768        25.2 MB
    u16* wt  = (u16*)(ws + 25165824);            // 3x768x768 (W^T)   3.5 MB
    u16* qbf = (u16*)(ws + 28704768);            // 16384x768        25.2 MB
    u16* kbf = (u16*)(ws + 53870592);            // 16384x768        25.2 MB
    u16* vt  = (u16*)(ws + 79036416);            // 8x768x2048       25.2 MB
    u16* S   = (u16*)(ws + 104202240);           // 8x2048x2048      67.1 MB

    // 1. conversions
    cvt_x_kernel<<<dim3(12288), dim3(256), 0, stream>>>(
        (const float4*)x, (ushort4v*)xbf, 3145728);
    cvt_w_kernel<<<dim3(6912), dim3(256), 0, stream>>>(wk, wt);

    // 2. fused QKV projections (one dispatch, 18 col-tiles share x row-tiles)
    gemm_bt<0><<<dim3(2304), dim3(256), 0, stream>>>(
        xbf, wt, qbf, kbf, vt, 1.0f);

    // 3. logits: S_b = 0.125 * Q_b K_b^T   (batch <-> XCD)
    gemm_bt<1><<<dim3(2048), dim3(256), 0, stream>>>(
        qbf, kbf, S, nullptr, nullptr, 0.125f);

    // 4. softmax rows (in place, bf16)
    softmax_kernel<<<dim3(16384), dim3(256), 0, stream>>>(S);

    // 5. out_b = A_b V_b
    gemm_bt<2><<<dim3(768), dim3(256), 0, stream>>>(
        S, vt, out, nullptr, nullptr, 1.0f);
}